// Round 15
// baseline (172.841 us; speedup 1.0000x reference)
//
#include <hip/hip_runtime.h>

typedef __bf16 bf16x8 __attribute__((ext_vector_type(8)));
typedef __bf16 bf16x4v __attribute__((ext_vector_type(4)));
typedef float f32x4 __attribute__((ext_vector_type(4)));

typedef const void __attribute__((address_space(1)))* gas_ptr;
typedef void __attribute__((address_space(3)))* las_ptr;

__device__ __forceinline__ void gload16(const __bf16* g, __bf16* lds) {
  __builtin_amdgcn_global_load_lds((gas_ptr)g, (las_ptr)lds, 16, 0, 0);
}

// ---------------------------------------------------------------------------
// one-shot cast: x (8M f32) then Wk|Wq|Wv (1M each) -> contiguous bf16 at out
__global__ __launch_bounds__(256) void cast_all(
    const float* __restrict__ x, const float* __restrict__ w0,
    const float* __restrict__ w1, const float* __restrict__ w2,
    __bf16* __restrict__ out) {
  int i = blockIdx.x * 256 + threadIdx.x;  // float4 index; total 2,883,584
  const float* src;
  int off;
  if (i < 2097152) {
    src = x; off = i;
  } else {
    int j = i - 2097152;
    int seg = j >> 18;            // 262144 float4 per W
    off = j & 262143;
    src = (seg == 0) ? w0 : (seg == 1) ? w1 : w2;
  }
  float4 v = ((const float4*)src)[off];
  bf16x4v o = { (__bf16)v.x, (__bf16)v.y, (__bf16)v.z, (__bf16)v.w };
  ((bf16x4v*)out)[i] = o;
}

// ---------------------------------------------------------------------------
// V[b][s][c] -> Vt[b][c][s], 64x64 tiles, bf16x8 vector loads+stores
__global__ void transpose_k(const __bf16* __restrict__ V, __bf16* __restrict__ Vt,
                            int T, int C) {
  __shared__ __bf16 tile[64][68];
  int b = blockIdx.z;
  int s0 = blockIdx.x * 64, c0 = blockIdx.y * 64;
  const __bf16* Vb = V + (size_t)b * T * C;
  __bf16* Vtb = Vt + (size_t)b * C * T;
  const int t = threadIdx.x;                  // 256
  const int sr = t >> 3, e8 = (t & 7) * 8;
#pragma unroll
  for (int it = 0; it < 2; ++it) {
    int s = it * 32 + sr;
    bf16x8 v = *(const bf16x8*)&Vb[(size_t)(s0 + s) * C + c0 + e8];
#pragma unroll
    for (int j = 0; j < 8; ++j) tile[s][e8 + j] = v[j];
  }
  __syncthreads();
#pragma unroll
  for (int it = 0; it < 2; ++it) {
    int c = it * 32 + sr;
    bf16x8 o;
#pragma unroll
    for (int j = 0; j < 8; ++j) o[j] = tile[e8 + j][c];
    *(bf16x8*)&Vtb[(size_t)(c0 + c) * T + s0 + e8] = o;
  }
}

// ---------------------------------------------------------------------------
// r1-structure NT GEMM (measured best): 128x128 tile, 4 waves, BK=32,
// 32 KiB double-buffered LDS, __syncthreads drain, conflict-free both-sides
// XOR swizzle. setprio(1) around the MFMA cluster: 3-4 co-resident blocks/CU
// at independent phases (attn-like regime, m191) -> MFMA waves preempt
// other blocks' staging waves.
// MODE 0: proj  -> bf16 out + bias[z]; grid (64m, 8n, 3z)
// MODE 1: scores-> E = bf16 exp(v*scale-8), mask c>r; LDS-combined row
//   partials -> rpart[by][z*2048+r]. Flat 544, Z-MAJOR: z = f/136 (consec
//   blocks share K-panels in L2), t = f - 136z, sqrt triangular decode.
// MODE 2: PV -> f32 out * (1/sum); 1/sum from rpart[0..bx] fixed order.
//   Flat 512, bh fastest (8 consec blocks share the (z,by) Vt panel in L2),
//   pair (f, f+256) -> bx, 15-bx keeps the LPT balance.
template <int MODE>
__global__ __launch_bounds__(256) void gemm_nt(
    const __bf16* __restrict__ A, const __bf16* __restrict__ B, void* __restrict__ Out,
    int lda, int ldb, int ldo, int nkt_full,
    const float* __restrict__ bias0, const float* __restrict__ bias1,
    const float* __restrict__ bias2, float scale, float* __restrict__ rpart,
    size_t strideA_z, size_t strideB_z, size_t strideO_z) {
  int bx, by, z;
  if (MODE == 0) {
    bx = blockIdx.x; by = blockIdx.y; z = blockIdx.z;
  } else if (MODE == 1) {
    int f = blockIdx.x;           // 0..543
    z = f / 136;                  // z-major: panel locality
    int t = f - z * 136;          // 0..135 lower-tri tile index
    bx = (int)((sqrtf(8.f * (float)t + 1.f) - 1.f) * 0.5f);
    while ((bx + 1) * (bx + 2) / 2 <= t) ++bx;
    while (bx * (bx + 1) / 2 > t) --bx;
    by = t - bx * (bx + 1) / 2;
  } else {
    int f = blockIdx.x;           // 0..511
    int half = f >> 8, idx = f & 255;
    int bh = idx & 7;             // fastest: consec blocks share (z,by) Vt panel
    by = (idx >> 3) & 7;
    z = idx >> 6;
    bx = half ? bh : 15 - bh;     // pair (f, f+256) sums to 15 -> balanced
  }
  A += (size_t)z * strideA_z;
  B += (size_t)z * strideB_z;
  const int m0 = bx * 128;
  const int n0 = by * 128;
  int nkt = nkt_full;
  if (MODE == 2) nkt = min(nkt, (bx + 1) * 4);  // causal (BK=32)

  __shared__ __align__(16) __bf16 smA[2][128 * 32];
  __shared__ __align__(16) __bf16 smB[2][128 * 32];
  __shared__ float psum[128];  // MODE1: row partials; MODE2: 1/rowsum

  const int tid = threadIdx.x;
  const int lane = tid & 63;
  const int wave = tid >> 6;
  const int grow = lane >> 2;                              // staging row within 16
  const int gcol = ((lane & 3) ^ ((lane >> 3) & 3)) << 3;  // swizzled global chunk

  const __bf16* Ab = A + (size_t)m0 * lda;
  const __bf16* Bb = B + (size_t)n0 * ldb;

  auto stage = [&](int buf, int kt) {
    const int kofs = kt * 32 + gcol;
#pragma unroll
    for (int rr = 0; rr < 2; ++rr) {
      int br = rr * 64 + wave * 16;
      gload16(Ab + (size_t)(br + grow) * lda + kofs, &smA[buf][br * 32]);
      gload16(Bb + (size_t)(br + grow) * ldb + kofs, &smB[buf][br * 32]);
    }
  };

  f32x4 acc[4][4];
  const f32x4 zero = {0.f, 0.f, 0.f, 0.f};
#pragma unroll
  for (int m = 0; m < 4; ++m)
#pragma unroll
    for (int n = 0; n < 4; ++n) acc[m][n] = zero;

  const int wr = (wave >> 1) * 64;
  const int wc = (wave & 1) * 64;
  const int lr = lane & 15;
  const int kg = lane >> 4;
  const int phys = (kg ^ ((lr >> 1) & 3)) << 3;  // conflict-free read offset

  stage(0, 0);
  if (MODE == 1 && tid < 128) psum[tid] = 0.f;
  __syncthreads();
  int cur = 0;
  for (int kt = 0; kt < nkt; ++kt) {
    if (kt + 1 < nkt) stage(cur ^ 1, kt + 1);
    bf16x8 af[4], bfr[4];
#pragma unroll
    for (int m = 0; m < 4; ++m)
      af[m] = *(const bf16x8*)&smA[cur][(wr + m * 16 + lr) * 32 + phys];
#pragma unroll
    for (int n = 0; n < 4; ++n)
      bfr[n] = *(const bf16x8*)&smB[cur][(wc + n * 16 + lr) * 32 + phys];
    __builtin_amdgcn_s_setprio(1);
#pragma unroll
    for (int m = 0; m < 4; ++m)
#pragma unroll
      for (int n = 0; n < 4; ++n)
        acc[m][n] = __builtin_amdgcn_mfma_f32_16x16x32_bf16(af[m], bfr[n], acc[m][n], 0, 0, 0);
    __builtin_amdgcn_s_setprio(0);
    __syncthreads();
    cur ^= 1;
  }

  // MODE2: build 1/rowsum in LDS from rpart[0..bx] (fixed order, deterministic)
  if (MODE == 2) {
    if (tid < 128) {
      float s = 0.f;
      for (int j = 0; j <= bx; ++j)
        s += rpart[(size_t)j * 8192 + (size_t)z * 2048 + m0 + tid];
      psum[tid] = 1.f / s;
    }
    __syncthreads();
  }

  // epilogue: D row=(lane>>4)*4+i, col=lane&15 per 16x16 fragment
#pragma unroll
  for (int m = 0; m < 4; ++m) {
#pragma unroll
    for (int i = 0; i < 4; ++i) {
      int r = m0 + wr + m * 16 + kg * 4 + i;
      float ri = (MODE == 2) ? psum[r - m0] : 0.f;
      float rs = 0.f;
#pragma unroll
      for (int n = 0; n < 4; ++n) {
        int c = n0 + wc + n * 16 + lr;
        float v = acc[m][n][i];
        if (MODE == 0) {
          const float* bias = (z == 0) ? bias0 : (z == 1) ? bias1 : bias2;
          ((__bf16*)Out)[(size_t)z * strideO_z + (size_t)r * ldo + c] = (__bf16)(v + bias[c]);
        } else if (MODE == 1) {
          float e = (c <= r) ? __expf(v * scale - 8.0f) : 0.0f;
          ((__bf16*)Out)[(size_t)z * strideO_z + (size_t)r * ldo + c] = (__bf16)e;
          rs += e;
        } else {
          ((float*)Out)[(size_t)z * strideO_z + (size_t)r * ldo + c] = v * ri;
        }
      }
      if (MODE == 1) {
        // reduce rs across the 16 lanes (lr) sharing this row, then LDS-add
        // (2 waves contribute per row; commutative add -> deterministic)
#pragma unroll
        for (int off = 1; off < 16; off <<= 1) rs += __shfl_xor(rs, off);
        if (lr == 0) atomicAdd(&psum[r - m0], rs);
      }
    }
  }

  if (MODE == 1) {
    __syncthreads();
    if (tid < 128)
      rpart[(size_t)by * 8192 + (size_t)z * 2048 + m0 + tid] = psum[tid];
  }
}

// ---------------------------------------------------------------------------
extern "C" void kernel_launch(void* const* d_in, const int* in_sizes, int n_in,
                              void* d_out, int out_size, void* d_ws, size_t ws_size,
                              hipStream_t stream) {
  const float* x  = (const float*)d_in[0];
  const float* Wk = (const float*)d_in[1];
  const float* Wq = (const float*)d_in[2];
  const float* Wv = (const float*)d_in[3];
  const float* bk = (const float*)d_in[4];
  const float* bq = (const float*)d_in[5];
  const float* bv = (const float*)d_in[6];
  float* out = (float*)d_out;

  const int B = 4, T = 2048, C = 1024;
  const int M = B * T;  // 8192

  char* ws = (char*)d_ws;
  __bf16* x_bf  = (__bf16*)ws;                   // 16 MB
  __bf16* w_bf  = (__bf16*)(ws + 16777216);      // 6 MB (contiguous after x_bf)
  __bf16* kqv   = (__bf16*)(ws + 23068672);      // 48 MB (K|Q|V, each [M][C])
  __bf16* vt    = (__bf16*)(ws + 73400320);      // 16 MB (Vt [B][C][T])
  __bf16* E     = (__bf16*)(ws + 90177536);      // 32 MB (exp-scores bf16)
  float*  rpart = (float*)(ws + 123731968);      // 512 KB (16 x [4z x 2048] partials)

  // single fused cast: x + Wk + Wq + Wv -> bf16 (contiguous dest)
  cast_all<<<11264, 256, 0, stream>>>(x, Wk, Wq, Wv, x_bf);

  // QKV projection: [8192,1024] x [1024,1024]^T, z = {K,Q,V}
  gemm_nt<0><<<dim3(M / 128, C / 128, 3), 256, 0, stream>>>(
      x_bf, w_bf, kqv, C, C, C, C / 32, bk, bq, bv, 1.f, nullptr,
      (size_t)0, (size_t)C * C, (size_t)M * C);

  // V transpose -> Vt[b][c][s]
  transpose_k<<<dim3(T / 64, C / 64, B), 256, 0, stream>>>(
      kqv + 2 * (size_t)M * C, vt, T, C);

  // E = exp(K@Q^T/32 - 8) bf16, causal-masked, + per-block row partial sums.
  // Flat 544, z-major triangular decode (L2 panel sharing).
  gemm_nt<1><<<dim3(544), 256, 0, stream>>>(
      kqv, kqv + (size_t)M * C, E, C, C, T, C / 32, nullptr, nullptr, nullptr,
      0.03125f, rpart, (size_t)T * C, (size_t)T * C, (size_t)T * T);

  // out = (E @ V) / rowsum; flat 512, Vt-panel-sharing order, LPT pairs
  gemm_nt<2><<<dim3(512), 256, 0, stream>>>(
      E, vt, out, T, T, C, T / 32, nullptr, nullptr, nullptr, 1.f, rpart,
      (size_t)T * T, (size_t)C * T, (size_t)T * C);
}

// Round 16
// 159.024 us; speedup vs baseline: 1.0869x; 1.0869x over previous
//
#include <hip/hip_runtime.h>

typedef __bf16 bf16x8 __attribute__((ext_vector_type(8)));
typedef __bf16 bf16x4v __attribute__((ext_vector_type(4)));
typedef float f32x4 __attribute__((ext_vector_type(4)));

typedef const void __attribute__((address_space(1)))* gas_ptr;
typedef void __attribute__((address_space(3)))* las_ptr;

__device__ __forceinline__ void gload16(const __bf16* g, __bf16* lds) {
  __builtin_amdgcn_global_load_lds((gas_ptr)g, (las_ptr)lds, 16, 0, 0);
}

// ---------------------------------------------------------------------------
// one-shot cast: x (8M f32) then Wk|Wq|Wv (1M each) -> contiguous bf16 at out
__global__ __launch_bounds__(256) void cast_all(
    const float* __restrict__ x, const float* __restrict__ w0,
    const float* __restrict__ w1, const float* __restrict__ w2,
    __bf16* __restrict__ out) {
  int i = blockIdx.x * 256 + threadIdx.x;  // float4 index; total 2,883,584
  const float* src;
  int off;
  if (i < 2097152) {
    src = x; off = i;
  } else {
    int j = i - 2097152;
    int seg = j >> 18;            // 262144 float4 per W
    off = j & 262143;
    src = (seg == 0) ? w0 : (seg == 1) ? w1 : w2;
  }
  float4 v = ((const float4*)src)[off];
  bf16x4v o = { (__bf16)v.x, (__bf16)v.y, (__bf16)v.z, (__bf16)v.w };
  ((bf16x4v*)out)[i] = o;
}

// ---------------------------------------------------------------------------
// V[b][s][c] -> Vt[b][c][s], 64x64 tiles, bf16x8 vector loads+stores
__global__ void transpose_k(const __bf16* __restrict__ V, __bf16* __restrict__ Vt,
                            int T, int C) {
  __shared__ __bf16 tile[64][68];
  int b = blockIdx.z;
  int s0 = blockIdx.x * 64, c0 = blockIdx.y * 64;
  const __bf16* Vb = V + (size_t)b * T * C;
  __bf16* Vtb = Vt + (size_t)b * C * T;
  const int t = threadIdx.x;                  // 256
  const int sr = t >> 3, e8 = (t & 7) * 8;
#pragma unroll
  for (int it = 0; it < 2; ++it) {
    int s = it * 32 + sr;
    bf16x8 v = *(const bf16x8*)&Vb[(size_t)(s0 + s) * C + c0 + e8];
#pragma unroll
    for (int j = 0; j < 8; ++j) tile[s][e8 + j] = v[j];
  }
  __syncthreads();
#pragma unroll
  for (int it = 0; it < 2; ++it) {
    int c = it * 32 + sr;
    bf16x8 o;
#pragma unroll
    for (int j = 0; j < 8; ++j) o[j] = tile[e8 + j][c];
    *(bf16x8*)&Vtb[(size_t)(c0 + c) * T + s0 + e8] = o;
  }
}

// ---------------------------------------------------------------------------
// r1-structure NT GEMM (measured best): 128x128 tile, 4 waves, BK=32,
// 32 KiB double-buffered LDS (3 blocks/CU), plain __syncthreads drain,
// conflict-free both-sides XOR swizzle (r9/r10-verified).
// MODE 0: proj  -> bf16 out + bias[z]; grid (64m, 8n, 3z)
// MODE 1: scores-> E = bf16 exp(v*scale-8), mask c>r; per-row sums fused via
//         shfl_xor reduce + atomicAdd into rsum. Grid: flat 544 = 4z x 136
//         lower-tri tiles (sqrt decode) — no dead blocks.
// MODE 2: PV    -> f32 out / rsum[r], k-tiles causal-limited. Grid: flat 512,
//         pair (j, j+256) -> bx, 15-bx so every CU gets 68 K-tiles (LPT).
template <int MODE>
__global__ __launch_bounds__(256) void gemm_nt(
    const __bf16* __restrict__ A, const __bf16* __restrict__ B, void* __restrict__ Out,
    int lda, int ldb, int ldo, int nkt_full,
    const float* __restrict__ bias0, const float* __restrict__ bias1,
    const float* __restrict__ bias2, float scale, float* __restrict__ rsum,
    size_t strideA_z, size_t strideB_z, size_t strideO_z) {
  int bx, by, z;
  if (MODE == 0) {
    bx = blockIdx.x; by = blockIdx.y; z = blockIdx.z;
  } else if (MODE == 1) {
    int f = blockIdx.x;           // 0..543
    z = f & 3;
    int t = f >> 2;               // 0..135 lower-tri tile index
    bx = (int)((sqrtf(8.f * (float)t + 1.f) - 1.f) * 0.5f);
    while ((bx + 1) * (bx + 2) / 2 <= t) ++bx;
    while (bx * (bx + 1) / 2 > t) --bx;
    by = t - bx * (bx + 1) / 2;
  } else {
    int f = blockIdx.x;           // 0..511
    int half = f >> 8, idx = f & 255;
    int rem = idx & 31;
    by = rem >> 2; z = rem & 3;
    int bh = idx >> 5;            // 0..7
    bx = half ? bh : 15 - bh;     // pair sums to 15 -> balanced CU load
  }
  A += (size_t)z * strideA_z;
  B += (size_t)z * strideB_z;
  const int m0 = bx * 128;
  const int n0 = by * 128;
  int nkt = nkt_full;
  if (MODE == 2) nkt = min(nkt, (bx + 1) * 4);  // causal (BK=32)

  __shared__ __align__(16) __bf16 smA[2][128 * 32];
  __shared__ __align__(16) __bf16 smB[2][128 * 32];

  const int tid = threadIdx.x;
  const int lane = tid & 63;
  const int wave = tid >> 6;
  const int grow = lane >> 2;                              // staging row within 16
  const int gcol = ((lane & 3) ^ ((lane >> 3) & 3)) << 3;  // swizzled global chunk

  const __bf16* Ab = A + (size_t)m0 * lda;
  const __bf16* Bb = B + (size_t)n0 * ldb;

  auto stage = [&](int buf, int kt) {
    const int kofs = kt * 32 + gcol;
#pragma unroll
    for (int rr = 0; rr < 2; ++rr) {
      int br = rr * 64 + wave * 16;
      gload16(Ab + (size_t)(br + grow) * lda + kofs, &smA[buf][br * 32]);
      gload16(Bb + (size_t)(br + grow) * ldb + kofs, &smB[buf][br * 32]);
    }
  };

  f32x4 acc[4][4];
  const f32x4 zero = {0.f, 0.f, 0.f, 0.f};
#pragma unroll
  for (int m = 0; m < 4; ++m)
#pragma unroll
    for (int n = 0; n < 4; ++n) acc[m][n] = zero;

  const int wr = (wave >> 1) * 64;
  const int wc = (wave & 1) * 64;
  const int lr = lane & 15;
  const int kg = lane >> 4;
  const int phys = (kg ^ ((lr >> 1) & 3)) << 3;  // conflict-free read offset

  stage(0, 0);
  __syncthreads();
  int cur = 0;
  for (int kt = 0; kt < nkt; ++kt) {
    if (kt + 1 < nkt) stage(cur ^ 1, kt + 1);
    bf16x8 af[4], bfr[4];
#pragma unroll
    for (int m = 0; m < 4; ++m)
      af[m] = *(const bf16x8*)&smA[cur][(wr + m * 16 + lr) * 32 + phys];
#pragma unroll
    for (int n = 0; n < 4; ++n)
      bfr[n] = *(const bf16x8*)&smB[cur][(wc + n * 16 + lr) * 32 + phys];
#pragma unroll
    for (int m = 0; m < 4; ++m)
#pragma unroll
      for (int n = 0; n < 4; ++n)
        acc[m][n] = __builtin_amdgcn_mfma_f32_16x16x32_bf16(af[m], bfr[n], acc[m][n], 0, 0, 0);
    __syncthreads();
    cur ^= 1;
  }

  // epilogue: D row=(lane>>4)*4+i, col=lane&15 per 16x16 fragment
#pragma unroll
  for (int m = 0; m < 4; ++m) {
#pragma unroll
    for (int i = 0; i < 4; ++i) {
      int r = m0 + wr + m * 16 + kg * 4 + i;
      float ri = (MODE == 2) ? 1.0f / rsum[z * 2048 + r] : 0.f;
      float rs = 0.f;
#pragma unroll
      for (int n = 0; n < 4; ++n) {
        int c = n0 + wc + n * 16 + lr;
        float v = acc[m][n][i];
        if (MODE == 0) {
          const float* bias = (z == 0) ? bias0 : (z == 1) ? bias1 : bias2;
          ((__bf16*)Out)[(size_t)z * strideO_z + (size_t)r * ldo + c] = (__bf16)(v + bias[c]);
        } else if (MODE == 1) {
          float e = (c <= r) ? __expf(v * scale - 8.0f) : 0.0f;
          ((__bf16*)Out)[(size_t)z * strideO_z + (size_t)r * ldo + c] = (__bf16)e;
          rs += e;
        } else {
          ((float*)Out)[(size_t)z * strideO_z + (size_t)r * ldo + c] = v * ri;
        }
      }
      if (MODE == 1) {
        // reduce rs across the 16 lanes (lr) sharing this row, then one atomic
#pragma unroll
        for (int off = 1; off < 16; off <<= 1) rs += __shfl_xor(rs, off);
        if (lr == 0) atomicAdd(&rsum[z * 2048 + r], rs);
      }
    }
  }
}

// ---------------------------------------------------------------------------
extern "C" void kernel_launch(void* const* d_in, const int* in_sizes, int n_in,
                              void* d_out, int out_size, void* d_ws, size_t ws_size,
                              hipStream_t stream) {
  const float* x  = (const float*)d_in[0];
  const float* Wk = (const float*)d_in[1];
  const float* Wq = (const float*)d_in[2];
  const float* Wv = (const float*)d_in[3];
  const float* bk = (const float*)d_in[4];
  const float* bq = (const float*)d_in[5];
  const float* bv = (const float*)d_in[6];
  float* out = (float*)d_out;

  const int B = 4, T = 2048, C = 1024;
  const int M = B * T;  // 8192

  char* ws = (char*)d_ws;
  __bf16* x_bf = (__bf16*)ws;                    // 16 MB
  __bf16* w_bf = (__bf16*)(ws + 16777216);       // 6 MB (contiguous after x_bf)
  __bf16* kqv  = (__bf16*)(ws + 23068672);       // 48 MB (K|Q|V, each [M][C])
  __bf16* vt   = (__bf16*)(ws + 73400320);       // 16 MB (Vt [B][C][T])
  __bf16* E    = (__bf16*)(ws + 90177536);       // 32 MB (exp-scores bf16)
  float*  rsum = (float*)(ws + 123731968);       // 32 KB (per-row sum, atomics)

  // single fused cast: x + Wk + Wq + Wv -> bf16 (contiguous dest)
  cast_all<<<11264, 256, 0, stream>>>(x, Wk, Wq, Wv, x_bf);

  // zero the row-sum accumulator (re-zeroed every launch; graph-capture safe)
  hipMemsetAsync(rsum, 0, (size_t)M * sizeof(float), stream);

  // QKV projection: [8192,1024] x [1024,1024]^T, z = {K,Q,V}
  gemm_nt<0><<<dim3(M / 128, C / 128, 3), 256, 0, stream>>>(
      x_bf, w_bf, kqv, C, C, C, C / 32, bk, bq, bv, 1.f, nullptr,
      (size_t)0, (size_t)C * C, (size_t)M * C);

  // V transpose -> Vt[b][c][s]
  transpose_k<<<dim3(T / 64, C / 64, B), 256, 0, stream>>>(
      kqv + 2 * (size_t)M * C, vt, T, C);

  // E = exp(K@Q^T/32 - 8) bf16, causal-masked, + fused row sums (atomics).
  // Flat 544-block grid: 4 batches x 136 lower-tri tiles, no dead blocks.
  gemm_nt<1><<<dim3(544), 256, 0, stream>>>(
      kqv, kqv + (size_t)M * C, E, C, C, T, C / 32, nullptr, nullptr, nullptr,
      0.03125f, rsum, (size_t)T * C, (size_t)T * C, (size_t)T * T);

  // out = (E @ V) / rsum[r]; flat 512-block LPT-balanced grid
  gemm_nt<2><<<dim3(512), 256, 0, stream>>>(
      E, vt, out, T, T, C, T / 32, nullptr, nullptr, nullptr, 1.f, rsum,
      (size_t)T * T, (size_t)C * T, (size_t)T * C);
}